// Round 4
// baseline (327.567 us; speedup 1.0000x reference)
//
#include <hip/hip_runtime.h>
#include <hip/hip_cooperative_groups.h>
#include <math.h>

namespace cg = cooperative_groups;

// Problem constants
#define DDIM   1024
#define BATCH  2048
#define MROWS  16384
#define TEMP_INV 10.0f
#define EPSN   1e-8f

// Geometry: 1024 blocks x 256 threads, guaranteed co-resident (4 blocks/CU).
#define GBLK 1024
#define NTHR 256
#define ROWS_PER_BLK (MROWS / GBLK)   // 16 rows/block, 4 per wave

// ws layout: float4 units for big arrays, float units for loss partials
#define OFF_PART4 0                       // [GBLK][256] float4 partials (4 MB)
#define OFF_S4    (GBLK * 256)            // [256] float4 final s
#define OFF_LP    ((OFF_S4 + 256) * 4)    // BATCH floats (loss per pair)

__device__ __forceinline__ float wave_sum(float v) {
    v += __shfl_xor(v, 32);
    v += __shfl_xor(v, 16);
    v += __shfl_xor(v, 8);
    v += __shfl_xor(v, 4);
    v += __shfl_xor(v, 2);
    v += __shfl_xor(v, 1);
    return v;
}

__device__ __forceinline__ float softplus_stable(float d) {
    return fmaxf(d, 0.0f) + log1pf(expf(-fabsf(d)));
}

__device__ __forceinline__ void f4acc(float4& a, const float4 v) {
    a.x += v.x; a.y += v.y; a.z += v.z; a.w += v.w;
}

// ---- Phase 1: block's 16 rows of mb -> normalized-row sum tile (4 KB) ----
__device__ __forceinline__ void phase1(const float* __restrict__ mb,
                                       float4* __restrict__ ws4,
                                       float4* lds4, int bid, int tid) {
    const int lane = tid & 63;
    const int wave = tid >> 6;
    const int rbase = bid * ROWS_PER_BLK;

    float4 a0 = {0,0,0,0}, a1 = {0,0,0,0}, a2 = {0,0,0,0}, a3 = {0,0,0,0};

    #pragma unroll
    for (int k = 0; k < 4; ++k) {
        const int row = rbase + k * 4 + wave;
        const float4* rp = reinterpret_cast<const float4*>(mb + (size_t)row * DDIM);
        float4 v0 = rp[lane];
        float4 v1 = rp[64 + lane];
        float4 v2 = rp[128 + lane];
        float4 v3 = rp[192 + lane];

        float ssq = v0.x*v0.x + v0.y*v0.y + v0.z*v0.z + v0.w*v0.w
                  + v1.x*v1.x + v1.y*v1.y + v1.z*v1.z + v1.w*v1.w
                  + v2.x*v2.x + v2.y*v2.y + v2.z*v2.z + v2.w*v2.w
                  + v3.x*v3.x + v3.y*v3.y + v3.z*v3.z + v3.w*v3.w;
        ssq = wave_sum(ssq);
        float inv = 1.0f / fmaxf(sqrtf(ssq), EPSN);

        a0.x += v0.x*inv; a0.y += v0.y*inv; a0.z += v0.z*inv; a0.w += v0.w*inv;
        a1.x += v1.x*inv; a1.y += v1.y*inv; a1.z += v1.z*inv; a1.w += v1.w*inv;
        a2.x += v2.x*inv; a2.y += v2.y*inv; a2.z += v2.z*inv; a2.w += v2.w*inv;
        a3.x += v3.x*inv; a3.y += v3.y*inv; a3.z += v3.z*inv; a3.w += v3.w*inv;
    }

    lds4[wave * 256 + lane]        = a0;
    lds4[wave * 256 + 64 + lane]   = a1;
    lds4[wave * 256 + 128 + lane]  = a2;
    lds4[wave * 256 + 192 + lane]  = a3;
    __syncthreads();

    float4 t = lds4[tid];
    f4acc(t, lds4[256 + tid]);
    f4acc(t, lds4[512 + tid]);
    f4acc(t, lds4[768 + tid]);
    ws4[OFF_PART4 + (size_t)bid * 256 + tid] = t;
}

// ---- Phase 2: s[col] = sum of GBLK partial rows (blocks 0..63) ----
__device__ __forceinline__ void phase2(float4* __restrict__ ws4,
                                       float4* lds4, int bid, int tid) {
    const int r = tid >> 2;        // 0..63
    const int c = tid & 3;         // 4 consecutive float4 cols = 1 cache line
    const int col = bid * 4 + c;

    float4 acc = {0,0,0,0};
    #pragma unroll 4
    for (int k = 0; k < 16; ++k)
        f4acc(acc, ws4[OFF_PART4 + (size_t)(r + 64 * k) * 256 + col]);

    lds4[r * 4 + c] = acc;
    __syncthreads();
    if (r < 16) {
        float4 x = lds4[r * 4 + c];
        f4acc(x, lds4[(r + 16) * 4 + c]);
        f4acc(x, lds4[(r + 32) * 4 + c]);
        f4acc(x, lds4[(r + 48) * 4 + c]);
        lds4[r * 4 + c] = x;
    }
    __syncthreads();
    if (r < 4) {
        float4 x = lds4[r * 4 + c];
        f4acc(x, lds4[(r + 4) * 4 + c]);
        f4acc(x, lds4[(r + 8) * 4 + c]);
        f4acc(x, lds4[(r + 12) * 4 + c]);
        lds4[r * 4 + c] = x;
    }
    __syncthreads();
    if (tid < 4) {
        float4 x = lds4[tid];
        f4acc(x, lds4[4 + tid]);
        f4acc(x, lds4[8 + tid]);
        f4acc(x, lds4[12 + tid]);
        ws4[OFF_S4 + bid * 4 + tid] = x;
    }
}

// ---- Phase 3: 2 pairs per block; 2 waves per pair; loss partial per pair ----
__device__ __forceinline__ void phase3(const float* __restrict__ img,
                                       float* __restrict__ ws,
                                       const float4* __restrict__ ws4,
                                       float (*lds5)[5], int bid, int tid) {
    const int lane = tid & 63;
    const int wave = tid >> 6;
    const int pair = bid * 2 + (wave >> 1);
    const int half = wave & 1;
    const int base = half * 128 + lane;

    const float4* ap = reinterpret_cast<const float4*>(img) + (size_t)pair * 256;
    const float4* bp = reinterpret_cast<const float4*>(img) + (size_t)(pair + BATCH) * 256;

    float4 va0 = ap[base], va1 = ap[base + 64];
    float4 vb0 = bp[base], vb1 = bp[base + 64];
    float4 vs0 = ws4[OFF_S4 + base], vs1 = ws4[OFF_S4 + base + 64];

    float ssqa = va0.x*va0.x + va0.y*va0.y + va0.z*va0.z + va0.w*va0.w
               + va1.x*va1.x + va1.y*va1.y + va1.z*va1.z + va1.w*va1.w;
    float ssqb = vb0.x*vb0.x + vb0.y*vb0.y + vb0.z*vb0.z + vb0.w*vb0.w
               + vb1.x*vb1.x + vb1.y*vb1.y + vb1.z*vb1.z + vb1.w*vb1.w;
    float dab  = va0.x*vb0.x + va0.y*vb0.y + va0.z*vb0.z + va0.w*vb0.w
               + va1.x*vb1.x + va1.y*vb1.y + va1.z*vb1.z + va1.w*vb1.w;
    float das  = va0.x*vs0.x + va0.y*vs0.y + va0.z*vs0.z + va0.w*vs0.w
               + va1.x*vs1.x + va1.y*vs1.y + va1.z*vs1.z + va1.w*vs1.w;
    float dbs  = vb0.x*vs0.x + vb0.y*vs0.y + vb0.z*vs0.z + vb0.w*vs0.w
               + vb1.x*vs1.x + vb1.y*vs1.y + vb1.z*vs1.z + vb1.w*vs1.w;

    ssqa = wave_sum(ssqa);
    ssqb = wave_sum(ssqb);
    dab  = wave_sum(dab);
    das  = wave_sum(das);
    dbs  = wave_sum(dbs);

    if (lane == 0) {
        lds5[wave][0] = ssqa; lds5[wave][1] = ssqb; lds5[wave][2] = dab;
        lds5[wave][3] = das;  lds5[wave][4] = dbs;
    }
    __syncthreads();
    if (half == 0 && lane == 0) {
        const int w = wave;
        float sa = lds5[w][0] + lds5[w + 1][0];
        float sb = lds5[w][1] + lds5[w + 1][1];
        float ab = lds5[w][2] + lds5[w + 1][2];
        float as = lds5[w][3] + lds5[w + 1][3];
        float bs = lds5[w][4] + lds5[w + 1][4];
        float ia  = 1.0f / fmaxf(sqrtf(sa), EPSN);
        float ib  = 1.0f / fmaxf(sqrtf(sb), EPSN);
        float pos = ab * ia * ib * TEMP_INV;
        float na  = as * ia * TEMP_INV;
        float nb  = bs * ib * TEMP_INV;
        ws[OFF_LP + pair] = softplus_stable(na - pos) + softplus_stable(nb - pos);
    }
}

// ---- Phase 4: block 0 reduces BATCH loss partials -> scalar ----
__device__ __forceinline__ void phase4(const float* __restrict__ ws,
                                       float* __restrict__ out,
                                       float (*lds5)[5], int tid) {
    const int lane = tid & 63;
    const int wave = tid >> 6;
    float v = 0.0f;
    #pragma unroll
    for (int k = 0; k < 8; ++k)
        v += ws[OFF_LP + tid + 256 * k];
    v = wave_sum(v);
    __syncthreads();
    if (lane == 0) lds5[wave][0] = v;
    __syncthreads();
    if (tid == 0)
        out[0] = (lds5[0][0] + lds5[1][0] + lds5[2][0] + lds5[3][0])
                 * (1.0f / (2.0f * BATCH));
}

// ================= fused cooperative kernel =================
__global__ __launch_bounds__(NTHR, 4)
void fused_kernel(const float* __restrict__ mb, const float* __restrict__ img,
                  float* __restrict__ ws, float* __restrict__ out) {
    cg::grid_group grid = cg::this_grid();
    __shared__ float4 lds4[1024];    // 16 KB, reused each phase
    __shared__ float  lds5[4][5];
    const int tid = threadIdx.x;
    const int bid = blockIdx.x;
    float4* ws4 = reinterpret_cast<float4*>(ws);

    phase1(mb, ws4, lds4, bid, tid);
    grid.sync();
    if (bid < 64) phase2(ws4, lds4, bid, tid);
    grid.sync();
    phase3(img, ws, ws4, lds5, bid, tid);
    grid.sync();
    if (bid == 0) phase4(ws, out, lds5, tid);
}

// ================= non-cooperative fallback =================
__global__ __launch_bounds__(NTHR, 4)
void k_phase1(const float* __restrict__ mb, float* __restrict__ ws) {
    __shared__ float4 lds4[1024];
    phase1(mb, reinterpret_cast<float4*>(ws), lds4, blockIdx.x, threadIdx.x);
}
__global__ __launch_bounds__(NTHR)
void k_phase2(float* __restrict__ ws) {
    __shared__ float4 lds4[256];
    phase2(reinterpret_cast<float4*>(ws), lds4, blockIdx.x, threadIdx.x);
}
__global__ __launch_bounds__(NTHR)
void k_phase3(const float* __restrict__ img, float* __restrict__ ws) {
    __shared__ float lds5[4][5];
    phase3(img, ws, reinterpret_cast<const float4*>(ws), lds5,
           blockIdx.x, threadIdx.x);
}
__global__ __launch_bounds__(NTHR)
void k_phase4(const float* __restrict__ ws, float* __restrict__ out) {
    __shared__ float lds5[4][5];
    phase4(ws, out, lds5, threadIdx.x);
}

extern "C" void kernel_launch(void* const* d_in, const int* in_sizes, int n_in,
                              void* d_out, int out_size, void* d_ws, size_t ws_size,
                              hipStream_t stream) {
    const float* img = (const float*)d_in[0];   // [2B, D] fp32
    const float* mb  = (const float*)d_in[1];   // [M, D]  fp32
    float* out = (float*)d_out;
    float* ws  = (float*)d_ws;

    void* args[] = {(void*)&mb, (void*)&img, (void*)&ws, (void*)&out};
    hipError_t err = hipLaunchCooperativeKernel(
        reinterpret_cast<void*>(fused_kernel),
        dim3(GBLK), dim3(NTHR), args, 0, stream);

    if (err != hipSuccess) {
        (void)hipGetLastError();   // clear error, take fallback path
        hipLaunchKernelGGL(k_phase1, dim3(GBLK), dim3(NTHR), 0, stream, mb, ws);
        hipLaunchKernelGGL(k_phase2, dim3(64),   dim3(NTHR), 0, stream, ws);
        hipLaunchKernelGGL(k_phase3, dim3(GBLK), dim3(NTHR), 0, stream, img, ws);
        hipLaunchKernelGGL(k_phase4, dim3(1),    dim3(NTHR), 0, stream, ws, out);
    }
}

// Round 5
// 40.119 us; speedup vs baseline: 8.1649x; 8.1649x over previous
//
#include <hip/hip_runtime.h>
#include <math.h>

// Problem constants
#define DDIM   1024
#define BATCH  2048
#define MROWS  16384
#define TEMP_INV 10.0f
#define EPSN   1e-8f

// K1 geometry: 2048 blocks x 256 threads (4 waves), 8 rows/block, 2 rows/wave
#define NA_BLOCKS 2048
#define NA_THREADS 256
// K3 geometry: 1024 blocks x 256 threads, 2 pairs/block, 2 waves/pair
#define NC_BLOCKS 1024
#define NC_THREADS 256

// ws layout in float4 units
#define OFF_PART4 0                    // [2048][256] float4 partials (8 MB)
#define OFF_S4    (NA_BLOCKS * 256)    // [256] float4 final s

__device__ __forceinline__ float wave_sum(float v) {
    v += __shfl_xor(v, 32);
    v += __shfl_xor(v, 16);
    v += __shfl_xor(v, 8);
    v += __shfl_xor(v, 4);
    v += __shfl_xor(v, 2);
    v += __shfl_xor(v, 1);
    return v;
}

__device__ __forceinline__ float softplus_stable(float d) {
    return fmaxf(d, 0.0f) + log1pf(expf(-fabsf(d)));
}

__device__ __forceinline__ void f4acc(float4& a, const float4 v) {
    a.x += v.x; a.y += v.y; a.z += v.z; a.w += v.w;
}

// ---- K1: partial[block][d] = sum over the block's 8 rows of row/||row|| ----
// (round-3 mb_sum, unchanged: full occupancy, no atomics, coalesced write)
__global__ __launch_bounds__(NA_THREADS, 6)
void mb_sum_kernel(const float* __restrict__ mb, float* __restrict__ ws) {
    __shared__ float4 lds4[4][256];
    const int tid  = threadIdx.x;
    const int lane = tid & 63;
    const int wave = tid >> 6;
    const int rbase = blockIdx.x * 8;

    float4 a0 = {0,0,0,0}, a1 = {0,0,0,0}, a2 = {0,0,0,0}, a3 = {0,0,0,0};

    #pragma unroll
    for (int k = 0; k < 2; ++k) {
        const int row = rbase + k * 4 + wave;
        const float4* rp = reinterpret_cast<const float4*>(mb + (size_t)row * DDIM);
        float4 v0 = rp[lane];
        float4 v1 = rp[64 + lane];
        float4 v2 = rp[128 + lane];
        float4 v3 = rp[192 + lane];

        float ssq = v0.x*v0.x + v0.y*v0.y + v0.z*v0.z + v0.w*v0.w
                  + v1.x*v1.x + v1.y*v1.y + v1.z*v1.z + v1.w*v1.w
                  + v2.x*v2.x + v2.y*v2.y + v2.z*v2.z + v2.w*v2.w
                  + v3.x*v3.x + v3.y*v3.y + v3.z*v3.z + v3.w*v3.w;
        ssq = wave_sum(ssq);
        float inv = 1.0f / fmaxf(sqrtf(ssq), EPSN);

        a0.x += v0.x*inv; a0.y += v0.y*inv; a0.z += v0.z*inv; a0.w += v0.w*inv;
        a1.x += v1.x*inv; a1.y += v1.y*inv; a1.z += v1.z*inv; a1.w += v1.w*inv;
        a2.x += v2.x*inv; a2.y += v2.y*inv; a2.z += v2.z*inv; a2.w += v2.w*inv;
        a3.x += v3.x*inv; a3.y += v3.y*inv; a3.z += v3.z*inv; a3.w += v3.w*inv;
    }

    lds4[wave][lane]       = a0;
    lds4[wave][64 + lane]  = a1;
    lds4[wave][128 + lane] = a2;
    lds4[wave][192 + lane] = a3;
    __syncthreads();

    float4 t0 = lds4[0][tid], t1 = lds4[1][tid], t2 = lds4[2][tid], t3 = lds4[3][tid];
    float4 t;
    t.x = t0.x + t1.x + t2.x + t3.x;
    t.y = t0.y + t1.y + t2.y + t3.y;
    t.z = t0.z + t1.z + t2.z + t3.z;
    t.w = t0.w + t1.w + t2.w + t3.w;

    reinterpret_cast<float4*>(ws)[OFF_PART4 + (size_t)blockIdx.x * 256 + tid] = t;
}

// ---- K2: s[col] = sum of all 2048 partial rows; also zero out[0] ----
// 64 blocks x 256 threads; block handles 4 float4 columns. 8 MB read (L3-hot).
__global__ __launch_bounds__(256)
void s_reduce_kernel(float* __restrict__ ws, float* __restrict__ out) {
    __shared__ float4 lds4[256];
    const float4* part = reinterpret_cast<const float4*>(ws);
    const int tid = threadIdx.x;
    const int r = tid >> 2;            // 0..63
    const int c = tid & 3;             // 0..3
    const int col4 = blockIdx.x * 4 + c;

    float4 acc = {0,0,0,0};
    #pragma unroll 8
    for (int k = 0; k < 32; ++k)
        f4acc(acc, part[OFF_PART4 + (size_t)(r + 64 * k) * 256 + col4]);

    lds4[r * 4 + c] = acc;
    __syncthreads();
    #pragma unroll
    for (int stride = 32; stride >= 1; stride >>= 1) {
        if (r < stride) {
            float4 x = lds4[r * 4 + c];
            f4acc(x, lds4[(r + stride) * 4 + c]);
            lds4[r * 4 + c] = x;
        }
        __syncthreads();
    }
    if (tid < 4)
        reinterpret_cast<float4*>(ws)[OFF_S4 + blockIdx.x * 4 + tid] = lds4[tid];

    if (blockIdx.x == 0 && tid == 0) out[0] = 0.0f;
}

// ---- K3: 2 pairs/block, 2 waves/pair; one scaled atomicAdd per block ----
__global__ __launch_bounds__(NC_THREADS, 4)
void img_kernel(const float* __restrict__ img, const float* __restrict__ ws,
                float* __restrict__ out) {
    __shared__ float lds5[4][5];
    __shared__ float lds_loss[2];
    const int tid  = threadIdx.x;
    const int lane = tid & 63;
    const int wave = tid >> 6;
    const int pair = blockIdx.x * 2 + (wave >> 1);   // [0, BATCH)
    const int half = wave & 1;
    const int base = half * 128 + lane;

    const float4* ap = reinterpret_cast<const float4*>(img) + (size_t)pair * 256;
    const float4* bp = reinterpret_cast<const float4*>(img) + (size_t)(pair + BATCH) * 256;
    const float4* sp = reinterpret_cast<const float4*>(ws) + OFF_S4;

    float4 va0 = ap[base], va1 = ap[base + 64];
    float4 vb0 = bp[base], vb1 = bp[base + 64];
    float4 vs0 = sp[base], vs1 = sp[base + 64];

    float ssqa = va0.x*va0.x + va0.y*va0.y + va0.z*va0.z + va0.w*va0.w
               + va1.x*va1.x + va1.y*va1.y + va1.z*va1.z + va1.w*va1.w;
    float ssqb = vb0.x*vb0.x + vb0.y*vb0.y + vb0.z*vb0.z + vb0.w*vb0.w
               + vb1.x*vb1.x + vb1.y*vb1.y + vb1.z*vb1.z + vb1.w*vb1.w;
    float dab  = va0.x*vb0.x + va0.y*vb0.y + va0.z*vb0.z + va0.w*vb0.w
               + va1.x*vb1.x + va1.y*vb1.y + va1.z*vb1.z + va1.w*vb1.w;
    float das  = va0.x*vs0.x + va0.y*vs0.y + va0.z*vs0.z + va0.w*vs0.w
               + va1.x*vs1.x + va1.y*vs1.y + va1.z*vs1.z + va1.w*vs1.w;
    float dbs  = vb0.x*vs0.x + vb0.y*vs0.y + vb0.z*vs0.z + vb0.w*vs0.w
               + vb1.x*vs1.x + vb1.y*vs1.y + vb1.z*vs1.z + vb1.w*vs1.w;

    ssqa = wave_sum(ssqa);
    ssqb = wave_sum(ssqb);
    dab  = wave_sum(dab);
    das  = wave_sum(das);
    dbs  = wave_sum(dbs);

    if (lane == 0) {
        lds5[wave][0] = ssqa; lds5[wave][1] = ssqb; lds5[wave][2] = dab;
        lds5[wave][3] = das;  lds5[wave][4] = dbs;
    }
    __syncthreads();
    if (half == 0 && lane == 0) {
        const int w = wave;
        float sa = lds5[w][0] + lds5[w + 1][0];
        float sb = lds5[w][1] + lds5[w + 1][1];
        float ab = lds5[w][2] + lds5[w + 1][2];
        float as = lds5[w][3] + lds5[w + 1][3];
        float bs = lds5[w][4] + lds5[w + 1][4];
        float ia  = 1.0f / fmaxf(sqrtf(sa), EPSN);
        float ib  = 1.0f / fmaxf(sqrtf(sb), EPSN);
        float pos = ab * ia * ib * TEMP_INV;
        float na  = as * ia * TEMP_INV;
        float nb  = bs * ib * TEMP_INV;
        lds_loss[w >> 1] = softplus_stable(na - pos) + softplus_stable(nb - pos);
    }
    __syncthreads();
    if (tid == 0)
        atomicAdd(out, (lds_loss[0] + lds_loss[1]) * (1.0f / (2.0f * BATCH)));
}

extern "C" void kernel_launch(void* const* d_in, const int* in_sizes, int n_in,
                              void* d_out, int out_size, void* d_ws, size_t ws_size,
                              hipStream_t stream) {
    const float* img = (const float*)d_in[0];   // [2B, D] fp32
    const float* mb  = (const float*)d_in[1];   // [M, D]  fp32
    float* out = (float*)d_out;
    float* ws  = (float*)d_ws;

    hipLaunchKernelGGL(mb_sum_kernel,   dim3(NA_BLOCKS), dim3(NA_THREADS), 0, stream, mb, ws);
    hipLaunchKernelGGL(s_reduce_kernel, dim3(64),        dim3(256),        0, stream, ws, out);
    hipLaunchKernelGGL(img_kernel,      dim3(NC_BLOCKS), dim3(NC_THREADS), 0, stream, img, ws, out);
}